// Round 7
// baseline (12214.665 us; speedup 1.0000x reference)
//
#include <hip/hip_runtime.h>
#include <hip/hip_bf16.h>

#define H 2048
#define T 2048
#define INPUT 1024
#define FOURH 8192
#define NBLK 256
#define RING 512  // ring slots; epoch barrier every 256 steps bounds skew < 512

typedef __attribute__((ext_vector_type(8))) short bf16x8;
typedef __attribute__((ext_vector_type(4))) float f32x4_t;

__device__ __forceinline__ unsigned short f2bf(float f) {
  union { float f; unsigned u; } v; v.f = f;
  unsigned r = v.u + 0x7FFFu + ((v.u >> 16) & 1u);
  return (unsigned short)(r >> 16);
}

// ---------------- prep: bf16 conversions + dt_prev table + flag init ----------------
__global__ void prep_kernel(const float* __restrict__ x, const float* __restrict__ W_ih,
                            const float* __restrict__ time_, short* __restrict__ xb,
                            short* __restrict__ wb, float* __restrict__ dtp,
                            unsigned* __restrict__ flags) {
  size_t i = (size_t)blockIdx.x * blockDim.x + threadIdx.x;
  size_t stride = (size_t)gridDim.x * blockDim.x;
  if (i < (size_t)T * INPUT) xb[i] = (short)f2bf(x[i]);
  for (size_t j = i; j < (size_t)FOURH * INPUT; j += stride) wb[j] = (short)f2bf(W_ih[j]);
  if (i < T) dtp[i] = (i >= 2) ? (time_[i - 1] - time_[i - 2]) : 0.0f;
  if (i < NBLK) flags[i] = 0u;
}

// ---------------- xg GEMM: C[m][n] = sum_k x[m][k] * W_ih[n][k] + b_ih[n] + b_hh[n] ----
// 1D grid, n-panel outer / m inner: 128 consecutive blocks share one 128KB B-panel
// and sweep all of A (4MB) -> per-XCD L2 keeps A hot, B panel read once per XCD.
__global__ void __launch_bounds__(256)
gemm_xg(const short* __restrict__ A, const short* __restrict__ B,
        const float* __restrict__ b_ih, const float* __restrict__ b_hh,
        float* __restrict__ xg) {
  int wave = threadIdx.x >> 6;
  int lane = threadIdx.x & 63;
  int bid = blockIdx.x;
  int m0 = (bid & 127) << 4;
  int n0 = ((bid >> 7) << 6) + (wave << 4);
  int r16 = lane & 15, q = lane >> 4;
  const short* ap = A + (size_t)(m0 + r16) * INPUT + q * 8;
  const short* bp = B + (size_t)(n0 + r16) * INPUT + q * 8;
  f32x4_t acc = {0.f, 0.f, 0.f, 0.f};
#pragma unroll 4
  for (int k = 0; k < INPUT; k += 32) {
    bf16x8 av = *(const bf16x8*)(ap + k);
    bf16x8 bv = *(const bf16x8*)(bp + k);
    acc = __builtin_amdgcn_mfma_f32_16x16x32_bf16(av, bv, acc, 0, 0, 0);
  }
  int n = n0 + r16;
  float bias = b_ih[n] + b_hh[n];
#pragma unroll
  for (int r = 0; r < 4; ++r) {
    int m = m0 + q * 4 + r;
    xg[(size_t)m * FOURH + n] = acc[r] + bias;
  }
}

// ---------------- epoch barrier (only every 256 steps, for ring WAR bound) ------------
__device__ __forceinline__ void epoch_bar(unsigned* flags, unsigned e) {
  __syncthreads();
  if (threadIdx.x == 0)
    __hip_atomic_store(&flags[blockIdx.x], e, __ATOMIC_RELEASE, __HIP_MEMORY_SCOPE_AGENT);
  if (threadIdx.x < NBLK) {
    while (__hip_atomic_load(&flags[threadIdx.x], __ATOMIC_RELAXED,
                             __HIP_MEMORY_SCOPE_AGENT) < e) {
    }
  }
  __builtin_amdgcn_fence(__ATOMIC_ACQUIRE, "agent");
  __syncthreads();
}

// ---------------- persistent recurrence: packed 4B tagged dataflow ----------------
// 256 blocks x 512 thr (8 waves, 1 block/CU). wave w of block b owns hidden unit
// u = 8b+w: gate rows {u, H+u, 2H+u, 3H+u}; lane l owns columns {256p+4l+e},
// p=0..7, e=0..3 -> LDS dot reads are 8 conflict-free ds_read_b128 per lane and
// weight init loads are fully coalesced 16B/lane.
// Transport word (4B): hi16 = tag (t+1 for step-t input), lo16 = bf16(h*gamma).
// Poll: wave w covers slot words [256w,256w+256); lane l loads 16B (two 8B
// agent-atomic loads). LDS double-buffered -> single __syncthreads per step.
__global__ void __launch_bounds__(512, 2)
lstm_rec(const float* __restrict__ xg, const float* __restrict__ W_hh,
         const float* __restrict__ decay_w, const float* __restrict__ decay_b,
         const float* __restrict__ h0, const float* __restrict__ c0,
         const float* __restrict__ dtp, float* __restrict__ hs,
         unsigned* ring, unsigned* flags) {
  const int wave = threadIdx.x >> 6;
  const int lane = threadIdx.x & 63;
  const int u = (blockIdx.x << 3) + wave;
  __shared__ __align__(16) float lh[2][H];

  // weights: wreg[g][4p+e] = W_hh[g*H+u][256p + 4*lane + e]  (coalesced b128 loads)
  float wreg[4][32];
#pragma unroll
  for (int g = 0; g < 4; ++g) {
    const float* wr = W_hh + (size_t)(g * H + u) * H + (lane << 2);
#pragma unroll
    for (int p = 0; p < 8; ++p)
      *(f32x4_t*)&wreg[g][p << 2] = *(const f32x4_t*)(wr + (p << 8));
  }
  const float dw = decay_w[u], db = decay_b[u];
  float c = c0[u];
  if (lane == 0) {
    unsigned pk = (1u << 16) | (unsigned)f2bf(h0[u]);  // gamma[0]=1, tag=1
    __hip_atomic_store(&ring[u], pk, __ATOMIC_RELAXED, __HIP_MEMORY_SCOPE_AGENT);
  }

  for (int t = 0; t < T; ++t) {
    if ((t & 255) == 0 && t) epoch_bar(flags, (unsigned)(t >> 8));

    // off-critical-path prefetch: gate inputs + NEXT step's gamma (h-independent)
    float xi = 0.f, xf = 0.f, xgv = 0.f, xo = 0.f, gam = 0.f;
    if (lane == 0) {
      const float* xr = xg + (size_t)t * FOURH;
      xi = xr[u]; xf = xr[H + u]; xgv = xr[2 * H + u]; xo = xr[3 * H + u];
      if (t + 1 < T) gam = __expf(-fmaxf(0.f, dtp[t + 1] * dw + db));
    }

    // poll this wave's slice: 16B per lane via two 8B agent-atomic loads
    const unsigned want = (unsigned)t + 1u;
    const int wbase = (wave << 8) + (lane << 2);  // word index within slot
    unsigned long long* sp = (unsigned long long*)(
        ring + (((size_t)(t & (RING - 1)) << 11) | (unsigned)wbase));
    unsigned long long w0, w1;
    for (;;) {
      w0 = __hip_atomic_load(sp,     __ATOMIC_RELAXED, __HIP_MEMORY_SCOPE_AGENT);
      w1 = __hip_atomic_load(sp + 1, __ATOMIC_RELAXED, __HIP_MEMORY_SCOPE_AGENT);
      unsigned t0 = ((unsigned)w0) >> 16;
      unsigned t1 = (unsigned)(w0 >> 48);
      unsigned t2 = ((unsigned)w1) >> 16;
      unsigned t3 = (unsigned)(w1 >> 48);
      int bad = (t0 != want) | (t1 != want) | (t2 != want) | (t3 != want);
      if (!__any(bad)) break;
    }
    // unpack bf16 -> fp32 into this step's LDS buffer (single b128 write)
    float* lb = lh[t & 1];
    {
      f32x4_t hv;
      union { unsigned u; float f; } v;
      v.u = ((unsigned)w0 & 0xFFFFu) << 16;          hv.x = v.f;
      v.u = ((unsigned)(w0 >> 32) & 0xFFFFu) << 16;  hv.y = v.f;
      v.u = ((unsigned)w1 & 0xFFFFu) << 16;          hv.z = v.f;
      v.u = ((unsigned)(w1 >> 32) & 0xFFFFu) << 16;  hv.w = v.f;
      *(f32x4_t*)(lb + wbase) = hv;
    }
    __syncthreads();

    float a0 = 0.f, a1 = 0.f, a2 = 0.f, a3 = 0.f;
#pragma unroll
    for (int p = 0; p < 8; ++p) {
      f32x4_t h4 = *(const f32x4_t*)(lb + (p << 8) + (lane << 2));  // conflict-free b128
#pragma unroll
      for (int e = 0; e < 4; ++e) {
        float h = h4[e];
        a0 += wreg[0][(p << 2) + e] * h;
        a1 += wreg[1][(p << 2) + e] * h;
        a2 += wreg[2][(p << 2) + e] * h;
        a3 += wreg[3][(p << 2) + e] * h;
      }
    }
#pragma unroll
    for (int s = 32; s >= 1; s >>= 1) {
      a0 += __shfl_xor(a0, s);
      a1 += __shfl_xor(a1, s);
      a2 += __shfl_xor(a2, s);
      a3 += __shfl_xor(a3, s);
    }
    if (lane == 0) {
      float iv = a0 + xi;
      float fv = a1 + xf;
      float gv = a2 + xgv;
      float ov = a3 + xo;
      iv = 1.f / (1.f + __expf(-iv));
      fv = 1.f / (1.f + __expf(-fv));
      gv = tanhf(gv);
      ov = 1.f / (1.f + __expf(-ov));
      c = fv * c + iv * gv;
      float h = ov * tanhf(c);
      if (t + 1 < T) {  // publish FIRST (critical path), hs store after
        unsigned pk = (((unsigned)(t + 2)) << 16) | (unsigned)f2bf(h * gam);
        size_t slot = (size_t)((t + 1) & (RING - 1)) << 11;
        __hip_atomic_store(&ring[slot | (unsigned)u], pk, __ATOMIC_RELAXED,
                           __HIP_MEMORY_SCOPE_AGENT);
      }
      hs[(size_t)t * H + u] = h;  // pristine fp32 h for attention
    }
    // no trailing syncthreads: next step writes the other lh buffer; a wave in
    // step t+2's write phase would require all waves past sync(t+1) -> impossible
    // while any wave still reads lh[t&1].
  }
}

// ---------------- attention pooling ----------------
__global__ void attn_k(const float* __restrict__ hs, float* __restrict__ attn) {
  int t = blockIdx.x;
  const float* row = hs + (size_t)t * H;
  const float* hf = hs + (size_t)(T - 1) * H;
  float s = 0.f;
  for (int i = threadIdx.x; i < H; i += 256) s += row[i] * hf[i];
#pragma unroll
  for (int o = 32; o; o >>= 1) s += __shfl_down(s, o);
  __shared__ float wsum[4];
  if ((threadIdx.x & 63) == 0) wsum[threadIdx.x >> 6] = s;
  __syncthreads();
  if (threadIdx.x == 0) attn[t] = wsum[0] + wsum[1] + wsum[2] + wsum[3];
}

__global__ void softmax_k(float* __restrict__ a) {
  int tid = threadIdx.x;
  __shared__ float red[16];
  __shared__ float bcast;
  float m = -1e30f;
  for (int i = tid; i < T; i += 1024) m = fmaxf(m, a[i]);
#pragma unroll
  for (int o = 32; o; o >>= 1) m = fmaxf(m, __shfl_xor(m, o));
  if ((tid & 63) == 0) red[tid >> 6] = m;
  __syncthreads();
  if (tid == 0) {
    float mm = red[0];
    for (int i = 1; i < 16; ++i) mm = fmaxf(mm, red[i]);
    bcast = mm;
  }
  __syncthreads();
  float M = bcast, s = 0.f;
  for (int i = tid; i < T; i += 1024) { float e = __expf(a[i] - M); a[i] = e; s += e; }
#pragma unroll
  for (int o = 32; o; o >>= 1) s += __shfl_xor(s, o);
  if ((tid & 63) == 0) red[tid >> 6] = s;
  __syncthreads();
  if (tid == 0) {
    float ss = 0.f;
    for (int i = 0; i < 16; ++i) ss += red[i];
    bcast = 1.f / ss;
  }
  __syncthreads();
  float inv = bcast;
  for (int i = tid; i < T; i += 1024) a[i] *= inv;
}

__global__ void ctx_k(const float* __restrict__ hs, const float* __restrict__ w,
                      float* __restrict__ out) {
  int h = (blockIdx.x << 8) + threadIdx.x;
  int t0 = blockIdx.y << 6;
  float acc = 0.f;
  for (int t = t0; t < t0 + 64; ++t) acc += w[t] * hs[(size_t)t * H + h];
  atomicAdd(&out[h], acc);
}

// ---------------- launch ----------------
extern "C" void kernel_launch(void* const* d_in, const int* in_sizes, int n_in,
                              void* d_out, int out_size, void* d_ws, size_t ws_size,
                              hipStream_t stream) {
  const float* x       = (const float*)d_in[0];
  const float* time_   = (const float*)d_in[1];
  const float* W_ih    = (const float*)d_in[2];
  const float* W_hh    = (const float*)d_in[3];
  const float* b_ih    = (const float*)d_in[4];
  const float* b_hh    = (const float*)d_in[5];
  const float* decay_w = (const float*)d_in[6];
  const float* decay_b = (const float*)d_in[7];
  const float* h0      = (const float*)d_in[8];
  const float* c0      = (const float*)d_in[9];

  char* ws = (char*)d_ws;
  float*    xg   = (float*)ws;                          // 64 MB  [T][4H]
  float*    hs   = (float*)(ws + (64u << 20));          // 16 MB  [T][H]
  short*    xb   = (short*)(ws + (80u << 20));          // 4 MB
  short*    wb   = (short*)(ws + (84u << 20));          // 16 MB
  unsigned* ring = (unsigned*)(ws + (100u << 20));      // 4 MB [RING][H] packed 4B
  float*    dtp  = (float*)(ws + (108u << 20));
  float*    attn = dtp + T;
  unsigned* flags = (unsigned*)(attn + T);

  prep_kernel<<<8192, 256, 0, stream>>>(x, W_ih, time_, xb, wb, dtp, flags);

  gemm_xg<<<16384, 256, 0, stream>>>(xb, wb, b_ih, b_hh, xg);

  {
    void* args[] = {&xg, (void*)&W_hh, (void*)&decay_w, (void*)&decay_b,
                    (void*)&h0, (void*)&c0, &dtp, &hs, &ring, &flags};
    (void)hipLaunchCooperativeKernel((void*)lstm_rec, dim3(NBLK), dim3(512), args, 0, stream);
  }

  attn_k<<<T, 256, 0, stream>>>(hs, attn);
  softmax_k<<<1, 1024, 0, stream>>>(attn);
  (void)hipMemsetAsync(d_out, 0, out_size * sizeof(float), stream);
  ctx_k<<<dim3(H / 256, T / 64), 256, 0, stream>>>(hs, attn, (float*)d_out);
}

// Round 8
// 6436.687 us; speedup vs baseline: 1.8977x; 1.8977x over previous
//
#include <hip/hip_runtime.h>
#include <hip/hip_bf16.h>

#define H 2048
#define T 2048
#define INPUT 1024
#define FOURH 8192
#define NBLK 256
#define RING 512  // ring slots; epoch barrier every 256 steps bounds skew < 512

typedef __attribute__((ext_vector_type(8))) short bf16x8;
typedef __attribute__((ext_vector_type(4))) float f32x4_t;

__device__ __forceinline__ unsigned short f2bf(float f) {
  union { float f; unsigned u; } v; v.f = f;
  unsigned r = v.u + 0x7FFFu + ((v.u >> 16) & 1u);
  return (unsigned short)(r >> 16);
}

// ---------------- prep: bf16 conversions + dt_prev table + flag init ----------------
__global__ void prep_kernel(const float* __restrict__ x, const float* __restrict__ W_ih,
                            const float* __restrict__ time_, short* __restrict__ xb,
                            short* __restrict__ wb, float* __restrict__ dtp,
                            unsigned* __restrict__ flags) {
  size_t i = (size_t)blockIdx.x * blockDim.x + threadIdx.x;
  size_t stride = (size_t)gridDim.x * blockDim.x;
  if (i < (size_t)T * INPUT) xb[i] = (short)f2bf(x[i]);
  for (size_t j = i; j < (size_t)FOURH * INPUT; j += stride) wb[j] = (short)f2bf(W_ih[j]);
  if (i < T) dtp[i] = (i >= 2) ? (time_[i - 1] - time_[i - 2]) : 0.0f;
  if (i < NBLK) flags[i] = 0u;
}

// ---------------- xg GEMM: C[m][n] = sum_k x[m][k] * W_ih[n][k] + b_ih[n] + b_hh[n] ----
// 1D grid, n-panel outer / m inner: 128 consecutive blocks share one B-panel and
// sweep all of A -> per-XCD L2 keeps A hot.
__global__ void __launch_bounds__(256)
gemm_xg(const short* __restrict__ A, const short* __restrict__ B,
        const float* __restrict__ b_ih, const float* __restrict__ b_hh,
        float* __restrict__ xg) {
  int wave = threadIdx.x >> 6;
  int lane = threadIdx.x & 63;
  int bid = blockIdx.x;
  int m0 = (bid & 127) << 4;
  int n0 = ((bid >> 7) << 6) + (wave << 4);
  int r16 = lane & 15, q = lane >> 4;
  const short* ap = A + (size_t)(m0 + r16) * INPUT + q * 8;
  const short* bp = B + (size_t)(n0 + r16) * INPUT + q * 8;
  f32x4_t acc = {0.f, 0.f, 0.f, 0.f};
#pragma unroll 4
  for (int k = 0; k < INPUT; k += 32) {
    bf16x8 av = *(const bf16x8*)(ap + k);
    bf16x8 bv = *(const bf16x8*)(bp + k);
    acc = __builtin_amdgcn_mfma_f32_16x16x32_bf16(av, bv, acc, 0, 0, 0);
  }
  int n = n0 + r16;
  float bias = b_ih[n] + b_hh[n];
#pragma unroll
  for (int r = 0; r < 4; ++r) {
    int m = m0 + q * 4 + r;
    xg[(size_t)m * FOURH + n] = acc[r] + bias;
  }
}

// ---------------- epoch barrier (only every 256 steps, for ring WAR bound) ------------
__device__ __forceinline__ void epoch_bar(unsigned* flags, unsigned e) {
  __syncthreads();
  if (threadIdx.x == 0)
    __hip_atomic_store(&flags[blockIdx.x], e, __ATOMIC_RELEASE, __HIP_MEMORY_SCOPE_AGENT);
  if (threadIdx.x < NBLK) {
    while (__hip_atomic_load(&flags[threadIdx.x], __ATOMIC_RELAXED,
                             __HIP_MEMORY_SCOPE_AGENT) < e) {
    }
  }
  __builtin_amdgcn_fence(__ATOMIC_ACQUIRE, "agent");
  __syncthreads();
}

// ---------------- persistent recurrence: tagged 8B dataflow (R5 skeleton) -------------
// 256 blocks x 512 thr (8 waves, 1 block/CU). wave w of block b owns hidden unit
// u = 8b+w: gate rows {u, H+u, 2H+u, 3H+u}; lane l owns columns {256p+4l+e},
// p=0..7, e=0..3 -> dot phase reads 8 conflict-free ds_read_b128 per lane.
// Transport (8B): hi32 = tag (t+1 for step-t input), lo32 = bits(h*gamma) fp32.
// Poll: wave w covers slot words [256w,256w+256); lane l loads 4x8B stride-64
// (lane-contiguous 512B per instruction). LDS layout identity: lh[i] = h_i.
// TWO syncthreads per step: the trailing one keeps the publish store ahead of the
// next step's poll flood (removing it doubled step time in R7).
__global__ void __launch_bounds__(512, 2)
lstm_rec(const float* __restrict__ xg, const float* __restrict__ W_hh,
         const float* __restrict__ decay_w, const float* __restrict__ decay_b,
         const float* __restrict__ h0, const float* __restrict__ c0,
         const float* __restrict__ dtp, float* __restrict__ hs,
         unsigned long long* ring, unsigned* flags) {
  const int wave = threadIdx.x >> 6;
  const int lane = threadIdx.x & 63;
  const int u = (blockIdx.x << 3) + wave;
  __shared__ __align__(16) float lh[H];

  // weights: wreg[g][4p+e] = W_hh[g*H+u][256p + 4*lane + e]  (coalesced b128 loads)
  float wreg[4][32];
#pragma unroll
  for (int g = 0; g < 4; ++g) {
    const float* wr = W_hh + (size_t)(g * H + u) * H + (lane << 2);
#pragma unroll
    for (int p = 0; p < 8; ++p)
      *(f32x4_t*)&wreg[g][p << 2] = *(const f32x4_t*)(wr + (p << 8));
  }
  const float dw = decay_w[u], db = decay_b[u];
  float c = c0[u];
  if (lane == 0) {
    union { float f; unsigned u; } hv; hv.f = h0[u];  // gamma[0] = 1, tag = 1
    __hip_atomic_store(&ring[u], (1ull << 32) | hv.u, __ATOMIC_RELAXED,
                       __HIP_MEMORY_SCOPE_AGENT);
  }

  for (int t = 0; t < T; ++t) {
    if ((t & 255) == 0 && t) epoch_bar(flags, (unsigned)(t >> 8));

    // off-critical-path prefetch: gate inputs + NEXT step's gamma (h-independent)
    float xi = 0.f, xf = 0.f, xgv = 0.f, xo = 0.f, gam = 0.f;
    if (lane == 0) {
      const float* xr = xg + (size_t)t * FOURH;
      xi = xr[u]; xf = xr[H + u]; xgv = xr[2 * H + u]; xo = xr[3 * H + u];
      if (t + 1 < T) gam = __expf(-fmaxf(0.f, dtp[t + 1] * dw + db));
    }

    // coalesced poll of this wave's 1/8 slice (4 x 8B per lane, lane-contiguous)
    const unsigned want = (unsigned)t + 1u;
    unsigned long long* sp =
        ring + (((size_t)(t & (RING - 1)) << 11) | (unsigned)((wave << 8) + lane));
    unsigned long long w0, w1, w2, w3;
    for (;;) {
      w0 = __hip_atomic_load(sp,       __ATOMIC_RELAXED, __HIP_MEMORY_SCOPE_AGENT);
      w1 = __hip_atomic_load(sp + 64,  __ATOMIC_RELAXED, __HIP_MEMORY_SCOPE_AGENT);
      w2 = __hip_atomic_load(sp + 128, __ATOMIC_RELAXED, __HIP_MEMORY_SCOPE_AGENT);
      w3 = __hip_atomic_load(sp + 192, __ATOMIC_RELAXED, __HIP_MEMORY_SCOPE_AGENT);
      int bad = ((unsigned)(w0 >> 32) != want) | ((unsigned)(w1 >> 32) != want) |
                ((unsigned)(w2 >> 32) != want) | ((unsigned)(w3 >> 32) != want);
      if (!__any(bad)) break;
    }
    // dedup through LDS, identity layout lh[i] = h_i
    {
      float* lw = lh + (wave << 8) + lane;
      union { unsigned u; float f; } v;
      v.u = (unsigned)w0; lw[0]   = v.f;
      v.u = (unsigned)w1; lw[64]  = v.f;
      v.u = (unsigned)w2; lw[128] = v.f;
      v.u = (unsigned)w3; lw[192] = v.f;
    }
    __syncthreads();

    float a0 = 0.f, a1 = 0.f, a2 = 0.f, a3 = 0.f;
#pragma unroll
    for (int p = 0; p < 8; ++p) {
      f32x4_t h4 = *(const f32x4_t*)(lh + (p << 8) + (lane << 2));  // conflict-free b128
#pragma unroll
      for (int e = 0; e < 4; ++e) {
        float h = h4[e];
        a0 += wreg[0][(p << 2) + e] * h;
        a1 += wreg[1][(p << 2) + e] * h;
        a2 += wreg[2][(p << 2) + e] * h;
        a3 += wreg[3][(p << 2) + e] * h;
      }
    }
#pragma unroll
    for (int s = 32; s >= 1; s >>= 1) {
      a0 += __shfl_xor(a0, s);
      a1 += __shfl_xor(a1, s);
      a2 += __shfl_xor(a2, s);
      a3 += __shfl_xor(a3, s);
    }
    if (lane == 0) {
      float iv = a0 + xi;
      float fv = a1 + xf;
      float gv = a2 + xgv;
      float ov = a3 + xo;
      iv = 1.f / (1.f + __expf(-iv));
      fv = 1.f / (1.f + __expf(-fv));
      gv = tanhf(gv);
      ov = 1.f / (1.f + __expf(-ov));
      c = fv * c + iv * gv;
      float h = ov * tanhf(c);
      if (t + 1 < T) {  // publish FIRST (critical path), hs store after
        union { float f; unsigned u; } hv; hv.f = h * gam;
        size_t slot = (size_t)((t + 1) & (RING - 1)) << 11;
        __hip_atomic_store(&ring[slot | (unsigned)u],
                           (((unsigned long long)(t + 2)) << 32) | hv.u,
                           __ATOMIC_RELAXED, __HIP_MEMORY_SCOPE_AGENT);
      }
      hs[(size_t)t * H + u] = h;  // pristine fp32 h for attention
    }
    __syncthreads();  // keep publish ahead of next step's poll flood (see R7)
  }
}

// ---------------- attention pooling ----------------
__global__ void attn_k(const float* __restrict__ hs, float* __restrict__ attn) {
  int t = blockIdx.x;
  const float* row = hs + (size_t)t * H;
  const float* hf = hs + (size_t)(T - 1) * H;
  float s = 0.f;
  for (int i = threadIdx.x; i < H; i += 256) s += row[i] * hf[i];
#pragma unroll
  for (int o = 32; o; o >>= 1) s += __shfl_down(s, o);
  __shared__ float wsum[4];
  if ((threadIdx.x & 63) == 0) wsum[threadIdx.x >> 6] = s;
  __syncthreads();
  if (threadIdx.x == 0) attn[t] = wsum[0] + wsum[1] + wsum[2] + wsum[3];
}

__global__ void softmax_k(float* __restrict__ a) {
  int tid = threadIdx.x;
  __shared__ float red[16];
  __shared__ float bcast;
  float m = -1e30f;
  for (int i = tid; i < T; i += 1024) m = fmaxf(m, a[i]);
#pragma unroll
  for (int o = 32; o; o >>= 1) m = fmaxf(m, __shfl_xor(m, o));
  if ((tid & 63) == 0) red[tid >> 6] = m;
  __syncthreads();
  if (tid == 0) {
    float mm = red[0];
    for (int i = 1; i < 16; ++i) mm = fmaxf(mm, red[i]);
    bcast = mm;
  }
  __syncthreads();
  float M = bcast, s = 0.f;
  for (int i = tid; i < T; i += 1024) { float e = __expf(a[i] - M); a[i] = e; s += e; }
#pragma unroll
  for (int o = 32; o; o >>= 1) s += __shfl_xor(s, o);
  if ((tid & 63) == 0) red[tid >> 6] = s;
  __syncthreads();
  if (tid == 0) {
    float ss = 0.f;
    for (int i = 0; i < 16; ++i) ss += red[i];
    bcast = 1.f / ss;
  }
  __syncthreads();
  float inv = bcast;
  for (int i = tid; i < T; i += 1024) a[i] *= inv;
}

__global__ void ctx_k(const float* __restrict__ hs, const float* __restrict__ w,
                      float* __restrict__ out) {
  int h = (blockIdx.x << 8) + threadIdx.x;
  int t0 = blockIdx.y << 6;
  float acc = 0.f;
  for (int t = t0; t < t0 + 64; ++t) acc += w[t] * hs[(size_t)t * H + h];
  atomicAdd(&out[h], acc);
}

// ---------------- launch ----------------
extern "C" void kernel_launch(void* const* d_in, const int* in_sizes, int n_in,
                              void* d_out, int out_size, void* d_ws, size_t ws_size,
                              hipStream_t stream) {
  const float* x       = (const float*)d_in[0];
  const float* time_   = (const float*)d_in[1];
  const float* W_ih    = (const float*)d_in[2];
  const float* W_hh    = (const float*)d_in[3];
  const float* b_ih    = (const float*)d_in[4];
  const float* b_hh    = (const float*)d_in[5];
  const float* decay_w = (const float*)d_in[6];
  const float* decay_b = (const float*)d_in[7];
  const float* h0      = (const float*)d_in[8];
  const float* c0      = (const float*)d_in[9];

  char* ws = (char*)d_ws;
  float*    xg   = (float*)ws;                          // 64 MB  [T][4H]
  float*    hs   = (float*)(ws + (64u << 20));          // 16 MB  [T][H]
  short*    xb   = (short*)(ws + (80u << 20));          // 4 MB
  short*    wb   = (short*)(ws + (84u << 20));          // 16 MB
  unsigned long long* ring = (unsigned long long*)(ws + (100u << 20)); // 8 MB [RING][H]
  float*    dtp  = (float*)(ws + (108u << 20));
  float*    attn = dtp + T;
  unsigned* flags = (unsigned*)(attn + T);

  prep_kernel<<<8192, 256, 0, stream>>>(x, W_ih, time_, xb, wb, dtp, flags);

  gemm_xg<<<16384, 256, 0, stream>>>(xb, wb, b_ih, b_hh, xg);

  {
    void* args[] = {&xg, (void*)&W_hh, (void*)&decay_w, (void*)&decay_b,
                    (void*)&h0, (void*)&c0, &dtp, &hs, &ring, &flags};
    (void)hipLaunchCooperativeKernel((void*)lstm_rec, dim3(NBLK), dim3(512), args, 0, stream);
  }

  attn_k<<<T, 256, 0, stream>>>(hs, attn);
  softmax_k<<<1, 1024, 0, stream>>>(attn);
  (void)hipMemsetAsync(d_out, 0, out_size * sizeof(float), stream);
  ctx_k<<<dim3(H / 256, T / 64), 256, 0, stream>>>(hs, attn, (float*)d_out);
}